// Round 9
// baseline (202.302 us; speedup 1.0000x reference)
//
#include <hip/hip_runtime.h>
#include <hip/hip_bf16.h>

typedef short short8 __attribute__((ext_vector_type(8)));
typedef float f32x4 __attribute__((ext_vector_type(4)));
typedef unsigned short u16;
typedef u16 u16x8 __attribute__((ext_vector_type(8)));

static constexpr float kAlpha = 0.2f;

static __device__ inline u16 f2bf(float f) {
  __hip_bfloat16 h = __float2bfloat16(f);
  return *reinterpret_cast<u16*>(&h);
}
static __device__ inline float bf2f(u16 v) {
  unsigned int u = ((unsigned int)v) << 16;
  return __uint_as_float(u);
}

// ---------------- K1: hbT[b][o][n] = (X @ W)[b][n][o]  (bf16) ----------------
__global__ __launch_bounds__(256) void k1_hW(const float* __restrict__ X,
                                             const float* __restrict__ W,
                                             u16* __restrict__ hbT) {
  int row0 = blockIdx.x * 8;  // global row index over b*4096+n
  int o = threadIdx.x & 127;
  int g = threadIdx.x >> 7;   // 0..1
  __shared__ float Xs[8][128];
#pragma unroll
  for (int s = 0; s < 4; ++s) {
    int idx = threadIdx.x + s * 256;
    Xs[idx >> 7][idx & 127] = X[(size_t)row0 * 128 + idx];
  }
  __syncthreads();
  float acc[4] = {0.f, 0.f, 0.f, 0.f};
  for (int k = 0; k < 128; ++k) {
    float w = W[k * 128 + o];
#pragma unroll
    for (int s = 0; s < 4; ++s) acc[s] += Xs[g + 2 * s][k] * w;
  }
  int b = row0 >> 12;
  int n0 = row0 & 4095;
#pragma unroll
  for (int s = 0; s < 4; ++s)
    hbT[((size_t)b * 128 + o) * 4096 + n0 + g + 2 * s] = f2bf(acc[s]);
}

// ---------------- K1b: f1[b][n] = h.a1, f2[b][n] = h.a2 ----------------
__global__ __launch_bounds__(256) void k1b_f(const u16* __restrict__ hbT,
                                             const float* __restrict__ a1,
                                             const float* __restrict__ a2,
                                             float* __restrict__ f1,
                                             float* __restrict__ f2) {
  int idx = blockIdx.x * 256 + threadIdx.x;  // b*4096+n
  int b = idx >> 12;
  int n = idx & 4095;
  const u16* base = hbT + (size_t)b * 128 * 4096 + n;
  float s1 = 0.f, s2 = 0.f;
  for (int o = 0; o < 128; ++o) {
    float h = bf2f(base[(size_t)o * 4096]);
    s1 += h * a1[o];
    s2 += h * a2[o];
  }
  f1[idx] = s1;
  f2[idx] = s2;
}

// ---------------- K2: partial column sums of exp(adj*e), float4 ----------------
// grid = 4b * 16jt * 32ic = 2048 blocks x 256 thr
__global__ __launch_bounds__(256) void k2_dpart(const float* __restrict__ adj,
                                                const float* __restrict__ f1,
                                                const float* __restrict__ f2,
                                                float* __restrict__ dpart) {
  int bid = blockIdx.x;
  int ic = bid & 31;
  int jt = (bid >> 5) & 15;
  int b = bid >> 9;
  int t = threadIdx.x;
  int c = t & 63, r = t >> 6;
  int j = jt * 256 + c * 4;
  const size_t badj = (size_t)b * 4096 * 4096;
  f32x4 f2v = *reinterpret_cast<const f32x4*>(&f2[b * 4096 + j]);
  const float* f1p = f1 + b * 4096;
  int row0 = ic * 128 + r;
  f32x4 sum = (f32x4){0.f, 0.f, 0.f, 0.f};
#pragma unroll 8
  for (int s = 0; s < 32; ++s) {
    int row = row0 + 4 * s;
    f32x4 a = *reinterpret_cast<const f32x4*>(&adj[badj + (size_t)row * 4096 + j]);
    float f1r = f1p[row];
#pragma unroll
    for (int k = 0; k < 4; ++k) {
      float e = f1r + f2v[k];
      e = e >= 0.f ? e : kAlpha * e;
      sum[k] += __expf(a[k] * e);
    }
  }
  __shared__ f32x4 red[256];
  red[t] = sum;
  __syncthreads();
  if (t < 64) {
    f32x4 tt = red[t] + red[t + 64] + red[t + 128] + red[t + 192];
    *reinterpret_cast<f32x4*>(&dpart[(size_t)(b * 32 + ic) * 4096 + j]) = tt;
  }
}

// -------- K2b: rd=1/sum; hs[b][o][j] = hbT[b][o][j] * rd[b][j] (bf16) --------
// grid = 4b * 16jb * 8og = 512 blocks x 256 thr
__global__ __launch_bounds__(256) void k2b_scale(const float* __restrict__ dpart,
                                                 const u16* __restrict__ hbT,
                                                 u16* __restrict__ hs) {
  int bid = blockIdx.x;
  int og = bid & 7;
  int jb = (bid >> 3) & 15;
  int b = bid >> 7;
  int j = jb * 256 + threadIdx.x;
  float s = 0.f;
#pragma unroll
  for (int ic = 0; ic < 32; ++ic) s += dpart[(size_t)(b * 32 + ic) * 4096 + j];
  float rd = 1.0f / s;
  const u16* src = hbT + (size_t)b * 128 * 4096 + j;
  u16* dst = hs + (size_t)b * 128 * 4096 + j;
#pragma unroll 4
  for (int o = og * 16; o < og * 16 + 16; ++o) {
    dst[(size_t)o * 4096] = f2bf(bf2f(src[(size_t)o * 4096]) * rd);
  }
}

// ---------------- K3: out = P @ hs + bias + input (MFMA bf16) ----------------
// "K2-ified": grid 1024 blocks (4b x 256 i-tiles of 16) = 4 independent
// blocks/CU, 512 thr = 8 waves, 32 waves/CU (full occupancy). Tiny phases
// (BK=32): per thread-phase 24 B of loads, 1 MFMA/wave. LDS 20 KB/block,
// ~40 VGPR. Depth-2 register prefetch, lgkmcnt-only barriers, XCD swizzle.
#define LROW 36
#define BARRIER()                                      \
  {                                                    \
    asm volatile("s_waitcnt lgkmcnt(0)" ::: "memory"); \
    __builtin_amdgcn_s_barrier();                      \
  }
__global__ __launch_bounds__(512, 8) void k3_out(
    const float* __restrict__ adj, const u16* __restrict__ hs,
    const float* __restrict__ f1, const float* __restrict__ f2,
    const float* __restrict__ bias, const float* __restrict__ input,
    float* __restrict__ out) {
  int bid0 = blockIdx.x;
  int bid = ((bid0 & 7) << 7) | (bid0 >> 3);  // XCD swizzle (1024 % 8 == 0)
  int b = bid >> 8;
  int i0 = (bid & 255) * 16;
  int t = threadIdx.x;
  int lane = t & 63;
  int ch = t >> 6;  // wave id = o-16-slice

  __shared__ u16 As[2][16 * LROW];   // P tile [i][k]   (2.25 KB)
  __shared__ u16 Bs[2][128 * LROW];  // hs tile [o][k]  (18 KB)

  const size_t badj = (size_t)b * 4096 * 4096;
  const u16* hb = hs + (size_t)b * 128 * 4096;
  const float* f2b = f2 + b * 4096;

  // A staging map: thread covers (row rr, col cc) of the 16x32 adj tile
  int rr = t >> 5;        // 0..15
  int cc = t & 31;        // 0..31
  // B staging map: thread covers o=bo, 8 cols starting bc0
  int bo = t >> 2;        // 0..127
  int bc0 = (t & 3) * 8;  // 0..24

  float f1v = f1[b * 4096 + i0 + rr];

  int l15 = lane & 15;
  int l8 = (lane >> 4) * 8;

  f32x4 acc = (f32x4){0.f, 0.f, 0.f, 0.f};

  // depth-2 prefetch register sets (static names only)
  float raA, raB;    // adj value
  float rfA, rfB;    // f2 value
  u16x8 rbA, rbB;    // hs 8 cols

#define PREFETCH(S, J0)                                                  \
  {                                                                      \
    int jj = (J0) & 4095; /* tail prefetches wrap, values unused */      \
    ra##S = adj[badj + (size_t)(i0 + rr) * 4096 + jj + cc];              \
    rf##S = f2b[jj + cc];                                                \
    rb##S = *reinterpret_cast<const u16x8*>(hb + (size_t)bo * 4096 + jj + bc0); \
  }

#define STORE(S, BUF)                                                \
  {                                                                  \
    float e = f1v + rf##S;                                           \
    e = e >= 0.f ? e : kAlpha * e;                                   \
    As[BUF][rr * LROW + cc] = f2bf(__expf(ra##S * e));               \
    *reinterpret_cast<u16x8*>(&Bs[BUF][bo * LROW + bc0]) = rb##S;    \
  }

#define DOMFMA(BUF)                                                          \
  {                                                                          \
    short8 af = *reinterpret_cast<const short8*>(&As[BUF][l15 * LROW + l8]); \
    short8 bf = *reinterpret_cast<const short8*>(                            \
        &Bs[BUF][(16 * ch + l15) * LROW + l8]);                              \
    acc = __builtin_amdgcn_mfma_f32_16x16x32_bf16(af, bf, acc, 0, 0, 0);     \
  }

  // Prologue: fill the 2-deep pipeline.
  PREFETCH(A, 0);
  PREFETCH(B, 32);

  for (int j0 = 0; j0 < 4096; j0 += 64) {
    STORE(A, 0);
    BARRIER();
    DOMFMA(0);
    PREFETCH(A, j0 + 64);
    STORE(B, 1);
    BARRIER();
    DOMFMA(1);
    PREFETCH(B, j0 + 96);
  }

  // ---- epilogue: + bias + input ----
  int o = 16 * ch + l15;
  int rowbase = i0 + (lane >> 4) * 4;
#pragma unroll
  for (int q = 0; q < 4; ++q) {
    int i = rowbase + q;
    size_t oidx = ((size_t)b * 4096 + i) * 128 + o;
    out[oidx] = acc[q] + bias[i * 128 + o] + input[oidx];
  }
}

extern "C" void kernel_launch(void* const* d_in, const int* in_sizes, int n_in,
                              void* d_out, int out_size, void* d_ws, size_t ws_size,
                              hipStream_t stream) {
  const float* input = (const float*)d_in[0];
  const float* adj = (const float*)d_in[1];
  const float* W = (const float*)d_in[2];
  const float* a1 = (const float*)d_in[3];
  const float* a2 = (const float*)d_in[4];
  const float* bias = (const float*)d_in[5];
  float* out = (float*)d_out;

  char* ws = (char*)d_ws;
  u16* hbT = (u16*)(ws);                  // 4*128*4096*2 = 4,194,304 B
  float* f1 = (float*)(ws + 4194304);     // 65,536 B
  float* f2 = (float*)(ws + 4259840);     // 65,536 B
  float* dpart = (float*)(ws + 4325376);  // 4*32*4096*4 = 2,097,152 B
  u16* hs = (u16*)(ws + 6422528);         // 4,194,304 B

  k1_hW<<<2048, 256, 0, stream>>>(input, W, hbT);
  k1b_f<<<64, 256, 0, stream>>>(hbT, a1, a2, f1, f2);
  k2_dpart<<<2048, 256, 0, stream>>>(adj, f1, f2, dpart);
  k2b_scale<<<512, 256, 0, stream>>>(dpart, hbT, hs);
  k3_out<<<1024, 512, 0, stream>>>(adj, hs, f1, f2, bias, input, out);
}

// Round 10
// 136.900 us; speedup vs baseline: 1.4777x; 1.4777x over previous
//
#include <hip/hip_runtime.h>
#include <hip/hip_bf16.h>

typedef short short8 __attribute__((ext_vector_type(8)));
typedef float f32x4 __attribute__((ext_vector_type(4)));
typedef unsigned short u16;
typedef u16 u16x4 __attribute__((ext_vector_type(4)));
typedef u16 u16x8 __attribute__((ext_vector_type(8)));

static constexpr float kAlpha = 0.2f;

static __device__ inline u16 f2bf(float f) {
  __hip_bfloat16 h = __float2bfloat16(f);
  return *reinterpret_cast<u16*>(&h);
}
static __device__ inline float bf2f(u16 v) {
  unsigned int u = ((unsigned int)v) << 16;
  return __uint_as_float(u);
}

// ---- K1: hbT[b][o][n] = (X @ W)[b][n][o] (bf16); f1/f2 fused (LDS+shfl) ----
__global__ __launch_bounds__(256) void k1_hW(const float* __restrict__ X,
                                             const float* __restrict__ W,
                                             const float* __restrict__ a1,
                                             const float* __restrict__ a2,
                                             u16* __restrict__ hbT,
                                             float* __restrict__ f1,
                                             float* __restrict__ f2) {
  int row0 = blockIdx.x * 8;  // global row index over b*4096+n
  int o = threadIdx.x & 127;
  int g = threadIdx.x >> 7;   // 0..1
  __shared__ float Xs[8][128];
#pragma unroll
  for (int s = 0; s < 4; ++s) {
    int idx = threadIdx.x + s * 256;
    Xs[idx >> 7][idx & 127] = X[(size_t)row0 * 128 + idx];
  }
  __syncthreads();
  float acc[4] = {0.f, 0.f, 0.f, 0.f};
  for (int k = 0; k < 128; ++k) {
    float w = W[k * 128 + o];
#pragma unroll
    for (int s = 0; s < 4; ++s) acc[s] += Xs[g + 2 * s][k] * w;
  }
  int b = row0 >> 12;
  int n0 = row0 & 4095;
#pragma unroll
  for (int s = 0; s < 4; ++s)
    hbT[((size_t)b * 128 + o) * 4096 + n0 + g + 2 * s] = f2bf(acc[s]);

  // ---- fused f1/f2: per-row dot with a1/a2 ----
  float a1o = a1[o], a2o = a2[o];
  __syncthreads();  // done reading Xs
#pragma unroll
  for (int s = 0; s < 4; ++s) Xs[g + 2 * s][o] = acc[s] * a1o;
  __syncthreads();
  int r = threadIdx.x >> 5, c = threadIdx.x & 31;
  float s1 = Xs[r][c] + Xs[r][c + 32] + Xs[r][c + 64] + Xs[r][c + 96];
  s1 += __shfl_xor(s1, 1);
  s1 += __shfl_xor(s1, 2);
  s1 += __shfl_xor(s1, 4);
  s1 += __shfl_xor(s1, 8);
  s1 += __shfl_xor(s1, 16);
  if (c == 0) f1[b * 4096 + n0 + r] = s1;
  __syncthreads();
#pragma unroll
  for (int s = 0; s < 4; ++s) Xs[g + 2 * s][o] = acc[s] * a2o;
  __syncthreads();
  float s2 = Xs[r][c] + Xs[r][c + 32] + Xs[r][c + 64] + Xs[r][c + 96];
  s2 += __shfl_xor(s2, 1);
  s2 += __shfl_xor(s2, 2);
  s2 += __shfl_xor(s2, 4);
  s2 += __shfl_xor(s2, 8);
  s2 += __shfl_xor(s2, 16);
  if (c == 0) f2[b * 4096 + n0 + r] = s2;
}

// ---------------- K2: partial column sums of exp(adj*e), float4 ----------------
// grid = 4b * 16jt * 32ic = 2048 blocks x 256 thr
__global__ __launch_bounds__(256) void k2_dpart(const float* __restrict__ adj,
                                                const float* __restrict__ f1,
                                                const float* __restrict__ f2,
                                                float* __restrict__ dpart) {
  int bid = blockIdx.x;
  int ic = bid & 31;
  int jt = (bid >> 5) & 15;
  int b = bid >> 9;
  int t = threadIdx.x;
  int c = t & 63, r = t >> 6;
  int j = jt * 256 + c * 4;
  const size_t badj = (size_t)b * 4096 * 4096;
  f32x4 f2v = *reinterpret_cast<const f32x4*>(&f2[b * 4096 + j]);
  const float* f1p = f1 + b * 4096;
  int row0 = ic * 128 + r;
  f32x4 sum = (f32x4){0.f, 0.f, 0.f, 0.f};
#pragma unroll 8
  for (int s = 0; s < 32; ++s) {
    int row = row0 + 4 * s;
    f32x4 a = *reinterpret_cast<const f32x4*>(&adj[badj + (size_t)row * 4096 + j]);
    float f1r = f1p[row];
#pragma unroll
    for (int k = 0; k < 4; ++k) {
      float e = f1r + f2v[k];
      e = e >= 0.f ? e : kAlpha * e;
      sum[k] += __expf(a[k] * e);
    }
  }
  __shared__ f32x4 red[256];
  red[t] = sum;
  __syncthreads();
  if (t < 64) {
    f32x4 tt = red[t] + red[t + 64] + red[t + 128] + red[t + 192];
    *reinterpret_cast<f32x4*>(&dpart[(size_t)(b * 32 + ic) * 4096 + j]) = tt;
  }
}

// -------- K2b: rd=1/sum; hs[b][o][j] = hbT[b][o][j] * rd[b][j] (bf16) --------
__global__ __launch_bounds__(256) void k2b_scale(const float* __restrict__ dpart,
                                                 const u16* __restrict__ hbT,
                                                 u16* __restrict__ hs) {
  int bid = blockIdx.x;
  int og = bid & 7;
  int jb = (bid >> 3) & 15;
  int b = bid >> 7;
  int j = jb * 256 + threadIdx.x;
  float s = 0.f;
#pragma unroll
  for (int ic = 0; ic < 32; ++ic) s += dpart[(size_t)(b * 32 + ic) * 4096 + j];
  float rd = 1.0f / s;
  const u16* src = hbT + (size_t)b * 128 * 4096 + j;
  u16* dst = hs + (size_t)b * 128 * 4096 + j;
#pragma unroll 4
  for (int o = og * 16; o < og * 16 + 16; ++o) {
    dst[(size_t)o * 4096] = f2bf(bf2f(src[(size_t)o * 4096]) * rd);
  }
}

// ---------------- K3w: parts[b][jq] = P[:,jq] @ hs[:,jq]^T (MFMA) ----------------
// WIDE tile: 256 i-rows x 128 o per block, j-quarter split. grid 256 = 1/CU,
// 512 thr = 8 waves (4 row-quarters x 2 o-halves), acc 4x4 frags/wave.
// 32 sub-phases of BK=64: per phase 64KB adj/block (8x dwordx4/thread).
// Depth-2 register prefetch, lgkmcnt-only barriers, 108KB dbuf LDS.
#define LROWW 72
#define BARRIER()                                      \
  {                                                    \
    asm volatile("s_waitcnt lgkmcnt(0)" ::: "memory"); \
    __builtin_amdgcn_s_barrier();                      \
  }
__global__ __launch_bounds__(512) void k3w(const float* __restrict__ adj,
                                           const u16* __restrict__ hs,
                                           const float* __restrict__ f1,
                                           const float* __restrict__ f2,
                                           float* __restrict__ parts) {
  int bid0 = blockIdx.x;
  int bid = ((bid0 & 7) << 5) | (bid0 >> 3);  // XCD swizzle (256 % 8 == 0)
  int b = bid >> 6;
  int it = (bid >> 2) & 15;
  int jq = bid & 3;
  int i0 = it * 256;
  int jbase = jq * 1024;
  int t = threadIdx.x;
  int lane = t & 63;
  int w = t >> 6;
  int rw = w & 3;   // row quarter (64 rows)
  int cw = w >> 2;  // o half (64 cols)

  __shared__ u16 As[2][256 * LROWW];  // P tile  (36.9 KB x2)
  __shared__ u16 Bs[2][128 * LROWW];  // hs tile (18.4 KB x2)

  const size_t badj = (size_t)b * 4096 * 4096;
  const u16* hb = hs + (size_t)b * 128 * 4096;
  const float* f2b = f2 + b * 4096;

  // A staging: thread covers rows r0+32u (u=0..7), cols c0..c0+3
  int r0 = t >> 4;        // 0..31
  int c0 = (t & 15) * 4;  // 0..60
  // B staging: thread covers o=bo, 16 cols at bc0 (2x u16x8)
  int bo = t >> 2;         // 0..127
  int bc0 = (t & 3) * 16;  // 0..48

  float f1v[8];
#pragma unroll
  for (int u = 0; u < 8; ++u) f1v[u] = f1[b * 4096 + i0 + r0 + 32 * u];

  int l15 = lane & 15;
  int l8 = (lane >> 4) * 8;

  f32x4 acc[4][4];
#pragma unroll
  for (int rg = 0; rg < 4; ++rg)
#pragma unroll
    for (int n = 0; n < 4; ++n) acc[rg][n] = (f32x4){0.f, 0.f, 0.f, 0.f};

  const float* ap0 = adj + badj + (size_t)(i0 + r0) * 4096 + c0;

  // depth-2 prefetch register sets (static names only)
  f32x4 raA0, raA1, raA2, raA3, raA4, raA5, raA6, raA7;
  f32x4 raB0, raB1, raB2, raB3, raB4, raB5, raB6, raB7;
  f32x4 rfA, rfB;
  u16x8 rbA0, rbA1, rbB0, rbB1;

#define PF(S, JO)                                                         \
  {                                                                       \
    int jj = jbase + ((JO) & 1023); /* tail wraps in-quarter, unused */   \
    const float* ap = ap0 + jj;                                           \
    ra##S##0 = *reinterpret_cast<const f32x4*>(ap);                       \
    ra##S##1 = *reinterpret_cast<const f32x4*>(ap + (size_t)1 * 131072);  \
    ra##S##2 = *reinterpret_cast<const f32x4*>(ap + (size_t)2 * 131072);  \
    ra##S##3 = *reinterpret_cast<const f32x4*>(ap + (size_t)3 * 131072);  \
    ra##S##4 = *reinterpret_cast<const f32x4*>(ap + (size_t)4 * 131072);  \
    ra##S##5 = *reinterpret_cast<const f32x4*>(ap + (size_t)5 * 131072);  \
    ra##S##6 = *reinterpret_cast<const f32x4*>(ap + (size_t)6 * 131072);  \
    ra##S##7 = *reinterpret_cast<const f32x4*>(ap + (size_t)7 * 131072);  \
    rf##S = *reinterpret_cast<const f32x4*>(f2b + jj + c0);               \
    const u16* bp = hb + (size_t)bo * 4096 + jj + bc0;                    \
    rb##S##0 = *reinterpret_cast<const u16x8*>(bp);                       \
    rb##S##1 = *reinterpret_cast<const u16x8*>(bp + 8);                   \
  }

#define STU(S, U, BUF)                                                    \
  {                                                                       \
    u16x4 pv;                                                             \
    _Pragma("unroll") for (int k = 0; k < 4; ++k) {                       \
      float e = f1v[U] + rf##S[k];                                        \
      e = e >= 0.f ? e : kAlpha * e;                                      \
      pv[k] = f2bf(__expf(ra##S##U[k] * e));                              \
    }                                                                     \
    *reinterpret_cast<u16x4*>(&As[BUF][(r0 + 32 * U) * LROWW + c0]) = pv; \
  }

#define STORE(S, BUF)                                                     \
  {                                                                       \
    STU(S, 0, BUF) STU(S, 1, BUF) STU(S, 2, BUF) STU(S, 3, BUF)           \
    STU(S, 4, BUF) STU(S, 5, BUF) STU(S, 6, BUF) STU(S, 7, BUF)           \
    *reinterpret_cast<u16x8*>(&Bs[BUF][bo * LROWW + bc0]) = rb##S##0;     \
    *reinterpret_cast<u16x8*>(&Bs[BUF][bo * LROWW + bc0 + 8]) = rb##S##1; \
  }

#define DOMFMA(BUF)                                                                \
  {                                                                                \
    _Pragma("unroll") for (int kk = 0; kk < 64; kk += 32) {                        \
      short8 af0 = *reinterpret_cast<const short8*>(                               \
          &As[BUF][(rw * 64 + 0 * 16 + l15) * LROWW + kk + l8]);                   \
      short8 af1 = *reinterpret_cast<const short8*>(                               \
          &As[BUF][(rw * 64 + 1 * 16 + l15) * LROWW + kk + l8]);                   \
      short8 af2 = *reinterpret_cast<const short8*>(                               \
          &As[BUF][(rw * 64 + 2 * 16 + l15) * LROWW + kk + l8]);                   \
      short8 af3 = *reinterpret_cast<const short8*>(                               \
          &As[BUF][(rw * 64 + 3 * 16 + l15) * LROWW + kk + l8]);                   \
      _Pragma("unroll") for (int n = 0; n < 4; ++n) {                              \
        short8 bf = *reinterpret_cast<const short8*>(                              \
            &Bs[BUF][(cw * 64 + n * 16 + l15) * LROWW + kk + l8]);                 \
        acc[0][n] = __builtin_amdgcn_mfma_f32_16x16x32_bf16(af0, bf, acc[0][n], 0, 0, 0); \
        acc[1][n] = __builtin_amdgcn_mfma_f32_16x16x32_bf16(af1, bf, acc[1][n], 0, 0, 0); \
        acc[2][n] = __builtin_amdgcn_mfma_f32_16x16x32_bf16(af2, bf, acc[2][n], 0, 0, 0); \
        acc[3][n] = __builtin_amdgcn_mfma_f32_16x16x32_bf16(af3, bf, acc[3][n], 0, 0, 0); \
      }                                                                            \
    }                                                                              \
  }

  // Prologue: fill depth-2 pipeline.
  PF(A, 0);
  PF(B, 64);

  for (int j0 = 0; j0 < 1024; j0 += 128) {
    STORE(A, 0);
    BARRIER();
    DOMFMA(0);
    PF(A, j0 + 128);
    STORE(B, 1);
    BARRIER();
    DOMFMA(1);
    PF(B, j0 + 192);
  }

  // ---- write f32 partials: parts[b][jq][i][o] ----
  float* pq = parts + (size_t)(b * 4 + jq) * 4096 * 128;
#pragma unroll
  for (int rg = 0; rg < 4; ++rg) {
#pragma unroll
    for (int n = 0; n < 4; ++n) {
      int o = cw * 64 + n * 16 + l15;
#pragma unroll
      for (int q = 0; q < 4; ++q) {
        int i = i0 + rw * 64 + rg * 16 + (lane >> 4) * 4 + q;
        pq[(size_t)i * 128 + o] = acc[rg][n][q];
      }
    }
  }
}

// ------- K4: out = sum_jq parts + bias + input (all batches) -------
// grid 2048 x 256, one f32x4 per thread.
__global__ __launch_bounds__(256) void k4r(const float* __restrict__ parts,
                                           const float* __restrict__ bias,
                                           const float* __restrict__ input,
                                           float* __restrict__ out) {
  size_t v = (size_t)blockIdx.x * 256 + threadIdx.x;  // f32x4 index over all
  int b = (int)(v >> 17);       // 131072 f32x4 per batch
  size_t e = (v & 131071) * 4;  // within-batch f32 offset
  const float* pb = parts + (size_t)b * 4 * 524288;
  f32x4 s = *reinterpret_cast<const f32x4*>(&pb[e]);
  s += *reinterpret_cast<const f32x4*>(&pb[e + 524288]);
  s += *reinterpret_cast<const f32x4*>(&pb[e + 2 * 524288]);
  s += *reinterpret_cast<const f32x4*>(&pb[e + 3 * 524288]);
  s += *reinterpret_cast<const f32x4*>(&bias[e]);
  size_t ge = (size_t)b * 524288 + e;
  s += *reinterpret_cast<const f32x4*>(&input[ge]);
  *reinterpret_cast<f32x4*>(&out[ge]) = s;
}

extern "C" void kernel_launch(void* const* d_in, const int* in_sizes, int n_in,
                              void* d_out, int out_size, void* d_ws, size_t ws_size,
                              hipStream_t stream) {
  const float* input = (const float*)d_in[0];
  const float* adj = (const float*)d_in[1];
  const float* W = (const float*)d_in[2];
  const float* a1 = (const float*)d_in[3];
  const float* a2 = (const float*)d_in[4];
  const float* bias = (const float*)d_in[5];
  float* out = (float*)d_out;

  char* ws = (char*)d_ws;
  u16* hbT = (u16*)(ws);                   // 4,194,304 B
  float* f1 = (float*)(ws + 4194304);      // 65,536 B
  float* f2 = (float*)(ws + 4259840);      // 65,536 B
  float* dpart = (float*)(ws + 4325376);   // 2,097,152 B
  u16* hs = (u16*)(ws + 6422528);          // 4,194,304 B
  float* parts = (float*)(ws + 10616832);  // 4*4*4096*128*4 = 33,554,432 B

  k1_hW<<<2048, 256, 0, stream>>>(input, W, a1, a2, hbT, f1, f2);
  k2_dpart<<<2048, 256, 0, stream>>>(adj, f1, f2, dpart);
  k2b_scale<<<512, 256, 0, stream>>>(dpart, hbT, hs);
  k3w<<<256, 512, 0, stream>>>(adj, hs, f1, f2, parts);
  k4r<<<2048, 256, 0, stream>>>(parts, bias, input, out);
}

// Round 11
// 134.227 us; speedup vs baseline: 1.5072x; 1.0199x over previous
//
#include <hip/hip_runtime.h>
#include <hip/hip_bf16.h>

typedef short short8 __attribute__((ext_vector_type(8)));
typedef float f32x4 __attribute__((ext_vector_type(4)));
typedef unsigned short u16;
typedef u16 u16x4 __attribute__((ext_vector_type(4)));
typedef u16 u16x8 __attribute__((ext_vector_type(8)));

static constexpr float kAlpha = 0.2f;

static __device__ inline u16 f2bf(float f) {
  __hip_bfloat16 h = __float2bfloat16(f);
  return *reinterpret_cast<u16*>(&h);
}
static __device__ inline float bf2f(u16 v) {
  unsigned int u = ((unsigned int)v) << 16;
  return __uint_as_float(u);
}

// ---- K1: hbT[b][o][n] = (X @ W)[b][n][o] (bf16); f1/f2 fused (LDS+shfl) ----
__global__ __launch_bounds__(256) void k1_hW(const float* __restrict__ X,
                                             const float* __restrict__ W,
                                             const float* __restrict__ a1,
                                             const float* __restrict__ a2,
                                             u16* __restrict__ hbT,
                                             float* __restrict__ f1,
                                             float* __restrict__ f2) {
  int row0 = blockIdx.x * 8;  // global row index over b*4096+n
  int o = threadIdx.x & 127;
  int g = threadIdx.x >> 7;   // 0..1
  __shared__ float Xs[8][128];
#pragma unroll
  for (int s = 0; s < 4; ++s) {
    int idx = threadIdx.x + s * 256;
    Xs[idx >> 7][idx & 127] = X[(size_t)row0 * 128 + idx];
  }
  __syncthreads();
  float acc[4] = {0.f, 0.f, 0.f, 0.f};
  for (int k = 0; k < 128; ++k) {
    float w = W[k * 128 + o];
#pragma unroll
    for (int s = 0; s < 4; ++s) acc[s] += Xs[g + 2 * s][k] * w;
  }
  int b = row0 >> 12;
  int n0 = row0 & 4095;
#pragma unroll
  for (int s = 0; s < 4; ++s)
    hbT[((size_t)b * 128 + o) * 4096 + n0 + g + 2 * s] = f2bf(acc[s]);

  // ---- fused f1/f2: per-row dot with a1/a2 ----
  float a1o = a1[o], a2o = a2[o];
  __syncthreads();  // done reading Xs
#pragma unroll
  for (int s = 0; s < 4; ++s) Xs[g + 2 * s][o] = acc[s] * a1o;
  __syncthreads();
  int r = threadIdx.x >> 5, c = threadIdx.x & 31;
  float s1 = Xs[r][c] + Xs[r][c + 32] + Xs[r][c + 64] + Xs[r][c + 96];
  s1 += __shfl_xor(s1, 1);
  s1 += __shfl_xor(s1, 2);
  s1 += __shfl_xor(s1, 4);
  s1 += __shfl_xor(s1, 8);
  s1 += __shfl_xor(s1, 16);
  if (c == 0) f1[b * 4096 + n0 + r] = s1;
  __syncthreads();
#pragma unroll
  for (int s = 0; s < 4; ++s) Xs[g + 2 * s][o] = acc[s] * a2o;
  __syncthreads();
  float s2 = Xs[r][c] + Xs[r][c + 32] + Xs[r][c + 64] + Xs[r][c + 96];
  s2 += __shfl_xor(s2, 1);
  s2 += __shfl_xor(s2, 2);
  s2 += __shfl_xor(s2, 4);
  s2 += __shfl_xor(s2, 8);
  s2 += __shfl_xor(s2, 16);
  if (c == 0) f2[b * 4096 + n0 + r] = s2;
}

// ---------------- K2: partial column sums of exp(adj*e), float4 ----------------
// grid = 4b * 16jt * 32ic = 2048 blocks x 256 thr
__global__ __launch_bounds__(256) void k2_dpart(const float* __restrict__ adj,
                                                const float* __restrict__ f1,
                                                const float* __restrict__ f2,
                                                float* __restrict__ dpart) {
  int bid = blockIdx.x;
  int ic = bid & 31;
  int jt = (bid >> 5) & 15;
  int b = bid >> 9;
  int t = threadIdx.x;
  int c = t & 63, r = t >> 6;
  int j = jt * 256 + c * 4;
  const size_t badj = (size_t)b * 4096 * 4096;
  f32x4 f2v = *reinterpret_cast<const f32x4*>(&f2[b * 4096 + j]);
  const float* f1p = f1 + b * 4096;
  int row0 = ic * 128 + r;
  f32x4 sum = (f32x4){0.f, 0.f, 0.f, 0.f};
#pragma unroll 8
  for (int s = 0; s < 32; ++s) {
    int row = row0 + 4 * s;
    f32x4 a = *reinterpret_cast<const f32x4*>(&adj[badj + (size_t)row * 4096 + j]);
    float f1r = f1p[row];
#pragma unroll
    for (int k = 0; k < 4; ++k) {
      float e = f1r + f2v[k];
      e = e >= 0.f ? e : kAlpha * e;
      sum[k] += __expf(a[k] * e);
    }
  }
  __shared__ f32x4 red[256];
  red[t] = sum;
  __syncthreads();
  if (t < 64) {
    f32x4 tt = red[t] + red[t + 64] + red[t + 128] + red[t + 192];
    *reinterpret_cast<f32x4*>(&dpart[(size_t)(b * 32 + ic) * 4096 + j]) = tt;
  }
}

// ---------------- K3w: parts[b][jq] = att[:,jq] @ h[:,jq]  (MFMA) ----------------
// WIDE tile: 256 i-rows x 128 o per block, j-quarter split. grid 256 = 1/CU,
// 512 thr = 8 waves (4 row-quarters x 2 o-halves), acc 4x4 frags/wave.
// rd[j]=1/colsum computed in prologue from dpart (LDS table, kills K2b);
// A-staging folds rd: P = exp(adj*e)*rd. B = hbT raw. bf16 partials out.
#define LROWW 72
#define BARRIER()                                      \
  {                                                    \
    asm volatile("s_waitcnt lgkmcnt(0)" ::: "memory"); \
    __builtin_amdgcn_s_barrier();                      \
  }
__global__ __launch_bounds__(512) void k3w(const float* __restrict__ adj,
                                           const u16* __restrict__ hbT,
                                           const float* __restrict__ f1,
                                           const float* __restrict__ f2,
                                           const float* __restrict__ dpart,
                                           u16* __restrict__ parts) {
  int bid0 = blockIdx.x;
  int bid = ((bid0 & 7) << 5) | (bid0 >> 3);  // XCD swizzle (256 % 8 == 0)
  int b = bid >> 6;
  int it = (bid >> 2) & 15;
  int jq = bid & 3;
  int i0 = it * 256;
  int jbase = jq * 1024;
  int t = threadIdx.x;
  int lane = t & 63;
  int w = t >> 6;
  int rw = w & 3;   // row quarter (64 rows)
  int cw = w >> 2;  // o half (64 cols)

  __shared__ u16 As[2][256 * LROWW];  // P tile  (36.9 KB x2)
  __shared__ u16 Bs[2][128 * LROWW];  // h tile  (18.4 KB x2)
  __shared__ float rds[1024];         // 1/colsum for this j-quarter (4 KB)

  const size_t badj = (size_t)b * 4096 * 4096;
  const u16* hb = hbT + (size_t)b * 128 * 4096;
  const float* f2b = f2 + b * 4096;

  // A staging: thread covers rows r0+32u (u=0..7), cols c0..c0+3
  int r0 = t >> 4;        // 0..31
  int c0 = (t & 15) * 4;  // 0..60
  // B staging: thread covers o=bo, 16 cols at bc0 (2x u16x8)
  int bo = t >> 2;         // 0..127
  int bc0 = (t & 3) * 16;  // 0..48

  float f1v[8];
#pragma unroll
  for (int u = 0; u < 8; ++u) f1v[u] = f1[b * 4096 + i0 + r0 + 32 * u];

  int l15 = lane & 15;
  int l8 = (lane >> 4) * 8;

  f32x4 acc[4][4];
#pragma unroll
  for (int rg = 0; rg < 4; ++rg)
#pragma unroll
    for (int n = 0; n < 4; ++n) acc[rg][n] = (f32x4){0.f, 0.f, 0.f, 0.f};

  const float* ap0 = adj + badj + (size_t)(i0 + r0) * 4096 + c0;

  // depth-2 prefetch register sets (static names only)
  f32x4 raA0, raA1, raA2, raA3, raA4, raA5, raA6, raA7;
  f32x4 raB0, raB1, raB2, raB3, raB4, raB5, raB6, raB7;
  f32x4 rfA, rfB;
  u16x8 rbA0, rbA1, rbB0, rbB1;

#define PF(S, JO)                                                         \
  {                                                                       \
    int jj = jbase + ((JO) & 1023); /* tail wraps in-quarter, unused */   \
    const float* ap = ap0 + jj;                                           \
    ra##S##0 = *reinterpret_cast<const f32x4*>(ap);                       \
    ra##S##1 = *reinterpret_cast<const f32x4*>(ap + (size_t)1 * 131072);  \
    ra##S##2 = *reinterpret_cast<const f32x4*>(ap + (size_t)2 * 131072);  \
    ra##S##3 = *reinterpret_cast<const f32x4*>(ap + (size_t)3 * 131072);  \
    ra##S##4 = *reinterpret_cast<const f32x4*>(ap + (size_t)4 * 131072);  \
    ra##S##5 = *reinterpret_cast<const f32x4*>(ap + (size_t)5 * 131072);  \
    ra##S##6 = *reinterpret_cast<const f32x4*>(ap + (size_t)6 * 131072);  \
    ra##S##7 = *reinterpret_cast<const f32x4*>(ap + (size_t)7 * 131072);  \
    rf##S = *reinterpret_cast<const f32x4*>(f2b + jj + c0);               \
    const u16* bp = hb + (size_t)bo * 4096 + jj + bc0;                    \
    rb##S##0 = *reinterpret_cast<const u16x8*>(bp);                       \
    rb##S##1 = *reinterpret_cast<const u16x8*>(bp + 8);                   \
  }

#define STU(S, U, BUF)                                                    \
  {                                                                       \
    u16x4 pv;                                                             \
    _Pragma("unroll") for (int k = 0; k < 4; ++k) {                       \
      float e = f1v[U] + rf##S[k];                                        \
      e = e >= 0.f ? e : kAlpha * e;                                      \
      pv[k] = f2bf(__expf(ra##S##U[k] * e) * rdv[k]);                     \
    }                                                                     \
    *reinterpret_cast<u16x4*>(&As[BUF][(r0 + 32 * U) * LROWW + c0]) = pv; \
  }

#define STORE(S, BUF, JO)                                                 \
  {                                                                       \
    f32x4 rdv = *reinterpret_cast<const f32x4*>(&rds[((JO) & 1023) + c0]);\
    STU(S, 0, BUF) STU(S, 1, BUF) STU(S, 2, BUF) STU(S, 3, BUF)           \
    STU(S, 4, BUF) STU(S, 5, BUF) STU(S, 6, BUF) STU(S, 7, BUF)           \
    *reinterpret_cast<u16x8*>(&Bs[BUF][bo * LROWW + bc0]) = rb##S##0;     \
    *reinterpret_cast<u16x8*>(&Bs[BUF][bo * LROWW + bc0 + 8]) = rb##S##1; \
  }

#define DOMFMA(BUF)                                                                \
  {                                                                                \
    _Pragma("unroll") for (int kk = 0; kk < 64; kk += 32) {                        \
      short8 af0 = *reinterpret_cast<const short8*>(                               \
          &As[BUF][(rw * 64 + 0 * 16 + l15) * LROWW + kk + l8]);                   \
      short8 af1 = *reinterpret_cast<const short8*>(                               \
          &As[BUF][(rw * 64 + 1 * 16 + l15) * LROWW + kk + l8]);                   \
      short8 af2 = *reinterpret_cast<const short8*>(                               \
          &As[BUF][(rw * 64 + 2 * 16 + l15) * LROWW + kk + l8]);                   \
      short8 af3 = *reinterpret_cast<const short8*>(                               \
          &As[BUF][(rw * 64 + 3 * 16 + l15) * LROWW + kk + l8]);                   \
      _Pragma("unroll") for (int n = 0; n < 4; ++n) {                              \
        short8 bf = *reinterpret_cast<const short8*>(                              \
            &Bs[BUF][(cw * 64 + n * 16 + l15) * LROWW + kk + l8]);                 \
        acc[0][n] = __builtin_amdgcn_mfma_f32_16x16x32_bf16(af0, bf, acc[0][n], 0, 0, 0); \
        acc[1][n] = __builtin_amdgcn_mfma_f32_16x16x32_bf16(af1, bf, acc[1][n], 0, 0, 0); \
        acc[2][n] = __builtin_amdgcn_mfma_f32_16x16x32_bf16(af2, bf, acc[2][n], 0, 0, 0); \
        acc[3][n] = __builtin_amdgcn_mfma_f32_16x16x32_bf16(af3, bf, acc[3][n], 0, 0, 0); \
      }                                                                            \
    }                                                                              \
  }

  // Prologue A: issue first prefetches (latency hides under rd computation).
  PF(A, 0);
  PF(B, 64);

  // Prologue B: rd[j] = 1/colsum for this j-quarter (from dpart partials).
  {
    const float* dp = dpart + (size_t)b * 32 * 4096 + jbase;
#pragma unroll
    for (int u = 0; u < 2; ++u) {
      int jj = t * 2 + u;
      float s = 0.f;
#pragma unroll
      for (int ic = 0; ic < 32; ++ic) s += dp[(size_t)ic * 4096 + jj];
      rds[jj] = 1.0f / s;
    }
  }
  __syncthreads();  // rds visible (also drains prologue PFs; one-time cost)

  for (int j0 = 0; j0 < 1024; j0 += 128) {
    STORE(A, 0, j0);
    BARRIER();
    DOMFMA(0);
    PF(A, j0 + 128);
    STORE(B, 1, j0 + 64);
    BARRIER();
    DOMFMA(1);
    PF(B, j0 + 192);
  }

  // ---- write bf16 partials: parts[b][jq][i][o] ----
  u16* pq = parts + (size_t)(b * 4 + jq) * 4096 * 128;
#pragma unroll
  for (int rg = 0; rg < 4; ++rg) {
#pragma unroll
    for (int n = 0; n < 4; ++n) {
      int o = cw * 64 + n * 16 + l15;
#pragma unroll
      for (int q = 0; q < 4; ++q) {
        int i = i0 + rw * 64 + rg * 16 + (lane >> 4) * 4 + q;
        pq[(size_t)i * 128 + o] = f2bf(acc[rg][n][q]);
      }
    }
  }
}

// ------- K4: out = sum_jq parts(bf16) + bias + input (all batches) -------
// grid 2048 x 256, one f32x4-of-output per thread.
__global__ __launch_bounds__(256) void k4r(const u16* __restrict__ parts,
                                           const float* __restrict__ bias,
                                           const float* __restrict__ input,
                                           float* __restrict__ out) {
  size_t v = (size_t)blockIdx.x * 256 + threadIdx.x;  // f32x4 index over all
  int b = (int)(v >> 17);       // 131072 f32x4 per batch
  size_t e = (v & 131071) * 4;  // within-batch element offset
  const u16* pb = parts + (size_t)b * 4 * 524288;
  u16x4 p0 = *reinterpret_cast<const u16x4*>(&pb[e]);
  u16x4 p1 = *reinterpret_cast<const u16x4*>(&pb[e + 524288]);
  u16x4 p2 = *reinterpret_cast<const u16x4*>(&pb[e + 2 * 524288]);
  u16x4 p3 = *reinterpret_cast<const u16x4*>(&pb[e + 3 * 524288]);
  f32x4 bv = *reinterpret_cast<const f32x4*>(&bias[e]);
  size_t ge = (size_t)b * 524288 + e;
  f32x4 iv = *reinterpret_cast<const f32x4*>(&input[ge]);
  f32x4 s;
#pragma unroll
  for (int k = 0; k < 4; ++k)
    s[k] = bf2f(p0[k]) + bf2f(p1[k]) + bf2f(p2[k]) + bf2f(p3[k]) + bv[k] + iv[k];
  *reinterpret_cast<f32x4*>(&out[ge]) = s;
}

extern "C" void kernel_launch(void* const* d_in, const int* in_sizes, int n_in,
                              void* d_out, int out_size, void* d_ws, size_t ws_size,
                              hipStream_t stream) {
  const float* input = (const float*)d_in[0];
  const float* adj = (const float*)d_in[1];
  const float* W = (const float*)d_in[2];
  const float* a1 = (const float*)d_in[3];
  const float* a2 = (const float*)d_in[4];
  const float* bias = (const float*)d_in[5];
  float* out = (float*)d_out;

  char* ws = (char*)d_ws;
  u16* hbT = (u16*)(ws);                 // 4,194,304 B
  float* f1 = (float*)(ws + 4194304);    // 65,536 B
  float* f2 = (float*)(ws + 4259840);    // 65,536 B
  float* dpart = (float*)(ws + 4325376); // 2,097,152 B
  u16* parts = (u16*)(ws + 6422528);     // 4*4*4096*128*2 = 16,777,216 B

  k1_hW<<<2048, 256, 0, stream>>>(input, W, a1, a2, hbT, f1, f2);
  k2_dpart<<<2048, 256, 0, stream>>>(adj, f1, f2, dpart);
  k3w<<<256, 512, 0, stream>>>(adj, hbT, f1, f2, dpart, parts);
  k4r<<<2048, 256, 0, stream>>>(parts, bias, input, out);
}